// Round 2
// baseline (561.190 us; speedup 1.0000x reference)
//
#include <hip/hip_runtime.h>
#include <stdint.h>

// EdgeNetwork: out[E,64] = tanh(relu(concat(x)[E,97] @ W1^T + b1) @ W2^T + b2)
// bf16 MFMA (16x16x32), latency-optimized: 512-thread blocks (8 waves share one
// LDS weight copy -> 16 waves/CU), explicit next-tile global prefetch before the
// DS-ordering clobbers, rank-1 ef term folded into acc init, v_perm-packed bf16.

typedef float  f32x4  __attribute__((ext_vector_type(4)));
typedef short  short8 __attribute__((ext_vector_type(8)));
typedef unsigned int u32;

#define LDSPAD 104  // bf16 row stride: 96 data + 8 pad = 208 B = 13*16 B (b128-aligned, even bank spread)

__device__ __forceinline__ unsigned short f2bf(float f) {
  // round-half-up f32 -> bf16 (finite inputs; same 0.5-ulp bound as RNE)
  union { float f; unsigned u; } v; v.f = f;
  return (unsigned short)((v.u + 0x8000u) >> 16);
}

__device__ __forceinline__ u32 pk2(float lo, float hi) {
  // pack bf16(lo) | bf16(hi)<<16 in 3 VALU ops (2 adds + v_perm)
  union { float f; u32 u; } a, b; a.f = lo; b.f = hi;
  return __builtin_amdgcn_perm(b.u + 0x8000u, a.u + 0x8000u, 0x07060302u);
}

__global__ __launch_bounds__(512, 4)
void edge_net_kernel(const float* __restrict__ dstf,
                     const float* __restrict__ dsth,
                     const float* __restrict__ srcf,
                     const float* __restrict__ srch,
                     const float* __restrict__ ef,
                     const float* __restrict__ W1,   // [80][97]
                     const float* __restrict__ b1,   // [80]
                     const float* __restrict__ W2,   // [64][80]
                     const float* __restrict__ b2,   // [64]
                     float* __restrict__ out,        // [E][64]
                     int nT2, int E) {
  __shared__ unsigned short w1s[80 * LDSPAD];   // W1[n][k<96] as bf16
  __shared__ unsigned short w2s[64 * LDSPAD];   // W2[n][k<80] as bf16, k 80..95 zeroed
  __shared__ unsigned short hs [128 * LDSPAD];  // h tile (16 rows per wave, 8 waves)
  __shared__ float w1last[80];                  // W1[n][96] (edge_feat column)
  __shared__ float b1s[80];
  __shared__ float b2s[64];

  const int tid = threadIdx.x;

  // ---- one-time weight prep (amortized over ~15 tiles/block) ----
  for (int idx = tid; idx < 80 * 96; idx += 512) {
    int n = idx / 96, k = idx - n * 96;
    w1s[n * LDSPAD + k] = f2bf(W1[n * 97 + k]);
  }
  for (int idx = tid; idx < 64 * 96; idx += 512) {
    int n = idx / 96, k = idx - n * 96;
    w2s[n * LDSPAD + k] = (k < 80) ? f2bf(W2[n * 80 + k]) : (unsigned short)0;
  }
  for (int idx = tid; idx < 128 * LDSPAD; idx += 512) hs[idx] = 0;
  if (tid < 80) { w1last[tid] = W1[tid * 97 + 96]; b1s[tid] = b1[tid]; }
  if (tid < 64) { b2s[tid] = b2[tid]; }
  __syncthreads();

  const int wave = tid >> 6;    // 0..7
  const int lane = tid & 63;
  const int m    = lane & 15;   // MFMA row (A) / col (B, C/D)
  const int quad = lane >> 4;   // k-chunk selector / C-row group

  // lane-invariant epilogue constants (hoisted out of the tile loop)
  float bias1[5], wl[5], bias2[4];
  #pragma unroll
  for (int i = 0; i < 5; ++i) { bias1[i] = b1s[i * 16 + m]; wl[i] = w1last[i * 16 + m]; }
  #pragma unroll
  for (int j = 0; j < 4; ++j) bias2[j] = b2s[j * 16 + m];

  const int grid = gridDim.x;
  int tile = blockIdx.x;

  // raw double-buffer for the prefetched x fragments (+ ef)
  f32x4 xa[3][2];
  f32x4 ef4;

  // concat boundaries (16,48,64,96) are 8-aligned, so each 8-chunk lives in one array
#define LOADX(EB) do {                                        \
    const int e_ = (EB) + m;                                  \
    _Pragma("unroll")                                         \
    for (int t_ = 0; t_ < 3; ++t_) {                          \
      const int c_ = t_ * 4 + quad;                           \
      const float* p_;                                        \
      if (c_ < 2)      p_ = dstf + e_ * 16 + c_ * 8;          \
      else if (c_ < 6) p_ = dsth + e_ * 32 + (c_ - 2) * 8;    \
      else if (c_ < 8) p_ = srcf + e_ * 16 + (c_ - 6) * 8;    \
      else             p_ = srch + e_ * 32 + (c_ - 8) * 8;    \
      xa[t_][0] = *(const f32x4*)p_;                          \
      xa[t_][1] = *(const f32x4*)(p_ + 4);                    \
    }                                                         \
    ef4 = *(const f32x4*)(ef + (EB) + quad * 4);              \
  } while (0)

  int  eb  = tile * 128 + wave * 16;
  bool act = (tile < nT2) && (eb < E);
  if (act) LOADX(eb);

  for (; tile < nT2; tile += grid) {
    const int e0 = tile * 128 + wave * 16;

    // ---- convert current tile to A fragments + fold ef into acc init
    //      (consumes xa/ef4 BEFORE the prefetch overwrites them) ----
    union { short8 s; u32 u[4]; } af[3];
    f32x4 acc1[5];
    if (act) {
      #pragma unroll
      for (int t = 0; t < 3; ++t) {
        af[t].u[0] = pk2(xa[t][0][0], xa[t][0][1]);
        af[t].u[1] = pk2(xa[t][0][2], xa[t][0][3]);
        af[t].u[2] = pk2(xa[t][1][0], xa[t][1][1]);
        af[t].u[3] = pk2(xa[t][1][2], xa[t][1][3]);
      }
      // acc1 init = b1[n] + ef[e] * W1[n][96]  (rank-1 k=96 term)
      #pragma unroll
      for (int i = 0; i < 5; ++i) {
        #pragma unroll
        for (int r = 0; r < 4; ++r) acc1[i][r] = fmaf(ef4[r], wl[i], bias1[i]);
      }
    }

    // ---- prefetch next tile's x (hides HBM/L3 latency under 27 MFMAs) ----
    const int  tn   = tile + grid;
    const int  ebn  = tn * 128 + wave * 16;
    const bool actn = (ebn < E);   // tiles >= nT2 imply ebn >= E
    if (actn) LOADX(ebn);

    if (act) {
      // ---- GEMM1: h[16x80] = x[16x96] @ W1^T ----
      #pragma unroll
      for (int t = 0; t < 3; ++t) {
        #pragma unroll
        for (int i = 0; i < 5; ++i) {
          short8 bfr = *(const short8*)&w1s[(i * 16 + m) * LDSPAD + t * 32 + quad * 8];
          acc1[i] = __builtin_amdgcn_mfma_f32_16x16x32_bf16(af[t].s, bfr, acc1[i], 0, 0, 0);
        }
      }

      // ---- epilogue 1: relu, h -> LDS (C-layout scatter) ----
      #pragma unroll
      for (int i = 0; i < 5; ++i) {
        #pragma unroll
        for (int r = 0; r < 4; ++r) {
          float h = fmaxf(acc1[i][r], 0.0f);
          hs[(wave * 16 + quad * 4 + r) * LDSPAD + i * 16 + m] = f2bf(h);
        }
      }
      asm volatile("" ::: "memory");  // RAW: keep h writes before h reads (same-wave DS is in-order)

      // ---- GEMM2 A-fragments from LDS (A-layout reads) ----
      short8 hf[3];
      #pragma unroll
      for (int t = 0; t < 3; ++t)
        hf[t] = *(const short8*)&hs[(wave * 16 + m) * LDSPAD + t * 32 + quad * 8];
      asm volatile("" ::: "memory");  // WAR: keep these reads before next iteration's h writes

      // ---- GEMM2: out[16x64] = h[16x96] @ W2^T (k 80..95 zero on both sides) ----
      f32x4 acc2[4];
      #pragma unroll
      for (int j = 0; j < 4; ++j) acc2[j] = (f32x4){bias2[j], bias2[j], bias2[j], bias2[j]};
      #pragma unroll
      for (int t = 0; t < 3; ++t) {
        #pragma unroll
        for (int j = 0; j < 4; ++j) {
          short8 bfr = *(const short8*)&w2s[(j * 16 + m) * LDSPAD + t * 32 + quad * 8];
          acc2[j] = __builtin_amdgcn_mfma_f32_16x16x32_bf16(hf[t], bfr, acc2[j], 0, 0, 0);
        }
      }

      // ---- epilogue 2: tanh + store (NaN-safe: 1 - 2/(e^2y + 1)) ----
      #pragma unroll
      for (int j = 0; j < 4; ++j) {
        #pragma unroll
        for (int r = 0; r < 4; ++r) {
          float y  = acc2[j][r];
          float ex = __builtin_amdgcn_exp2f(y * 2.885390081777927f);  // e^(2y)
          float th = 1.0f - 2.0f * __builtin_amdgcn_rcpf(ex + 1.0f);
          out[(e0 + quad * 4 + r) * 64 + j * 16 + m] = th;
        }
      }
    }

    act = actn;
  }
#undef LOADX
}

extern "C" void kernel_launch(void* const* d_in, const int* in_sizes, int n_in,
                              void* d_out, int out_size, void* d_ws, size_t ws_size,
                              hipStream_t stream) {
  const float* dstf = (const float*)d_in[0];
  const float* dsth = (const float*)d_in[1];
  const float* srcf = (const float*)d_in[2];
  const float* srch = (const float*)d_in[3];
  const float* ef   = (const float*)d_in[4];
  const float* W1   = (const float*)d_in[5];
  const float* b1   = (const float*)d_in[6];
  const float* W2   = (const float*)d_in[7];
  const float* b2   = (const float*)d_in[8];
  float* out = (float*)d_out;

  const int E   = in_sizes[4];        // 1,000,000 (multiple of 64)
  const int nT2 = (E + 127) >> 7;     // 128 edges per block-iteration (8 waves x 16)
  int grid = 512;                     // 2 blocks/CU x 256 CUs, grid-stride persistent
  if (grid > nT2) grid = nT2;

  hipLaunchKernelGGL(edge_net_kernel, dim3(grid), dim3(512), 0, stream,
                     dstf, dsth, srcf, srch, ef, W1, b1, W2, b2, out, nT2, E);
}